// Round 13
// baseline (70.109 us; speedup 1.0000x reference)
//
#include <hip/hip_runtime.h>
#include <math.h>

#define NCLS 80
#define NB 16
#define NA 3
#define NT 100

// ---- hybrid obj-pass decomposition ----
// dense: rows [0, 201600) of o0  = f4 [0, 4284000), 1024-f4 slabs
// scattered: rows [201600, 403200), one 4B load/thread
static constexpr int NF4D       = 4284000;       // 201600*85/4
static constexpr int DEN_BLOCKS = 4184;          // ceil(4284000/1024)
static constexpr int SCT_BLOCKS = 788;           // ceil(201600/256)
static constexpr int WORKB      = DEN_BLOCKS + SCT_BLOCKS;  // 4972
static constexpr int A_TOTAL    = NB + WORKB;    // 4988

static constexpr int POS_BLOCKS = 400;           // 1600 waves
static constexpr int NEI_BLOCKS = 16;
static constexpr int REST_TOTAL = POS_BLOCKS + NEI_BLOCKS;  // 416

// local (per-image) cell encoding: s0 [0,6400), s1 [6400,8000), s2 [8000,8400)

__device__ double g_dpart[DEN_BLOCKS];     // dense partials (all scale 0)
__device__ double g_gpart[SCT_BLOCKS][3];  // scattered partials per scale
__device__ int    g_mainCnt[NB];
__device__ int    g_neiCnt [NB];
__device__ int    g_recN[NB*NT];           // global cell index of main winner
__device__ float  g_recW[NB*NT];           // weight (winner target)
__device__ float4 g_recB[NB*NT];           // bvec of lastAny target
__device__ uint4  g_recM[NB*NT];           // class mask words
__device__ int    g_neiList[NB*400];       // s | (objElem<<2)
__device__ double g_bpart[POS_BLOCKS][3];
__device__ double g_cpart[POS_BLOCKS][3];
__device__ double g_opart[POS_BLOCKS][3];
__device__ double g_ncorrPart[NEI_BLOCKS][3];
__device__ int    g_nposPart[NB][3];
__device__ unsigned g_done;                // reset by kA block 0

__device__ __forceinline__ float softplusf(float x) {
    return fmaxf(x, 0.0f) + log1pf(expf(-fabsf(x)));   // stable logaddexp(0,x)
}
__device__ __forceinline__ double wred64(double v) {
    #pragma unroll
    for (int o = 32; o > 0; o >>= 1) v += __shfl_xor(v, o);
    return v;
}
__device__ __forceinline__ int wredi(int v) {
    #pragma unroll
    for (int o = 32; o > 0; o >>= 1) v += __shfl_xor(v, o);
    return v;
}

// =============== Kernel A: winner ∥ dense-stream ∥ scattered-gather ===============
__global__ __launch_bounds__(256) void kA(const float* __restrict__ o0,
                                          const float* __restrict__ o1,
                                          const float* __restrict__ o2,
                                          const float* __restrict__ tgt) {
    // union-ish static LDS (sum across roles ~23KB -> ~6 blocks/CU)
    __shared__ float  ldsStage[4096];      // dense staging (16KB)
    __shared__ double sRed[4][3];          // reduction scratch (all roles)
    __shared__ int    sPK[NT];
    __shared__ int4   sNC[NT];
    __shared__ float  sB4[NT][4];
    __shared__ float  sWt[NT];
    __shared__ int    sCntM, sCntN, sNpos[3];

    int tid = threadIdx.x;
    if (blockIdx.x < NB) {
        // ------------------------------ winner role (proven R8) ------------------
        int b = blockIdx.x;
        if (tid == 0) { sCntM = 0; sCntN = 0; if (b == 0) g_done = 0u; }
        if (tid < 3) sNpos[tid] = 0;
        if (tid < NT) {
            const float* p = tgt + (size_t)(b*NT + tid) * 5;
            float x1 = fminf(fmaxf(p[0],0.f),1.f);
            float y1 = fminf(fmaxf(p[1],0.f),1.f);
            float x2 = fminf(fmaxf(p[2],0.f),1.f);
            float y2 = fminf(fmaxf(p[3],0.f),1.f);
            bool valid = (x2 > x1) && (y2 > y1);
            int pk = 0;
            int4 nc = make_int4(-1,-1,-1,-1);
            float area = 0.f;
            if (valid) {
                area = (x2-x1)*(y2-y1);
                int s  = (area <= 0.0025f) ? 0 : ((area <= 0.0225f) ? 1 : 2);
                int Wd = (s==0) ? 80 : ((s==1) ? 40 : 20);
                int LO = (s==0) ? 0  : ((s==1) ? 6400 : 8000);
                int gi = (int)floorf(0.5f*(x1+x2)*(float)Wd); gi = min(max(gi,0), Wd-1);
                int gj = (int)floorf(0.5f*(y1+y2)*(float)Wd); gj = min(max(gj,0), Wd-1);
                int cell = LO + gj*Wd + gi;
                int cid = (int)p[4];
                int clsok = (cid >= 0 && cid < NCLS) ? 1 : 0;
                int cidc = min(max(cid, 0), NCLS-1);
                int tiny = (area <= 0.0025f) ? 1 : 0;
                pk = cell | (1<<14) | (tiny<<15) | (cidc<<16) | (clsok<<24);
                if (tiny) {
                    nc.x = (gj-1 >= 0) ? (LO + (gj-1)*Wd + gi) : -1;
                    nc.y = (gj+1 < Wd) ? (LO + (gj+1)*Wd + gi) : -1;
                    nc.z = (gi-1 >= 0) ? (LO + gj*Wd + gi-1)   : -1;
                    nc.w = (gi+1 < Wd) ? (LO + gj*Wd + gi+1)   : -1;
                }
            }
            float smallness = 1.f - fminf(1.f, area / 0.0025f);
            sPK[tid] = pk; sNC[tid] = nc;
            sWt[tid] = 1.f + fmaxf(0.f, smallness);
            sB4[tid][0]=x1; sB4[tid][1]=y1; sB4[tid][2]=x2; sB4[tid][3]=y2;
        }
        __syncthreads();
        if (tid < NT) {
            int t = tid;
            int me = sPK[t];
            if (me & (1<<14)) {
                int C = me & 0x3FFF;
                bool lose = false; int la = t;
                unsigned m0=0, m1=0, m2=0;
                #pragma unroll 4
                for (int t2 = 0; t2 < NT; ++t2) {
                    int  w2 = sPK[t2];
                    int4 n2 = sNC[t2];
                    int  c2 = w2 & 0x3FFF;
                    bool v2 = (w2 & (1<<14)) != 0;
                    bool isMain = v2 && (c2 == C);
                    bool tch = (n2.x==C) | (n2.y==C) | (n2.z==C) | (n2.w==C);
                    bool touch = isMain | tch;
                    lose = lose | (isMain && (t2 > t));
                    if (touch) {
                        if (t2 > la) la = t2;
                        if (w2 & (1<<24)) {
                            int cd = (w2 >> 16) & 0xFF;
                            if (cd < 32)      m0 |= 1u << cd;
                            else if (cd < 64) m1 |= 1u << (cd-32);
                            else              m2 |= 1u << (cd-64);
                        }
                    }
                }
                if (!lose) {
                    int slot = atomicAdd(&sCntM, 1);
                    int s   = (C < 6400) ? 0 : ((C < 8000) ? 1 : 2);
                    int LO  = (s==0) ? 0 : ((s==1) ? 6400 : 8000);
                    int HWl = (s==0) ? 6400 : ((s==1) ? 1600 : 400);
                    int GO  = (s==0) ? 0 : ((s==1) ? 102400 : 128000);
                    int gidx = b*NT + slot;
                    g_recN[gidx] = GO + b*HWl + (C - LO);
                    g_recW[gidx] = sWt[t];
                    g_recB[gidx] = make_float4(sB4[la][0], sB4[la][1], sB4[la][2], sB4[la][3]);
                    g_recM[gidx] = make_uint4(m0, m1, m2, 0u);
                    atomicAdd(&sNpos[s], 1);
                }
            }
        }
        #pragma unroll
        for (int r = 0; r < 2; ++r) {
            int idx = tid + 256*r;
            if (idx < 400) {
                int t = idx >> 2, k = idx & 3;
                int me = sPK[t];
                if (me & (1<<15)) {    // tiny (implies valid)
                    int4 myn = sNC[t];
                    int C = (k==0) ? myn.x : ((k==1) ? myn.y : ((k==2) ? myn.z : myn.w));
                    if (C >= 0) {
                        bool dead = false;
                        #pragma unroll 4
                        for (int t2 = 0; t2 < NT; ++t2) {
                            int  w2 = sPK[t2];
                            int4 n2 = sNC[t2];
                            bool v2 = (w2 & (1<<14)) != 0;
                            int  c2 = w2 & 0x3FFF;
                            dead = dead | (v2 && (c2 == C));
                            dead = dead | ((t2 > t) && ((n2.x==C)|(n2.y==C)|(n2.z==C)|(n2.w==C)));
                        }
                        if (!dead) {
                            int slot = atomicAdd(&sCntN, 1);
                            int s   = (C < 6400) ? 0 : ((C < 8000) ? 1 : 2);
                            int LO  = (s==0) ? 0 : ((s==1) ? 6400 : 8000);
                            int HWl = (s==0) ? 6400 : ((s==1) ? 1600 : 400);
                            int elem = b * NA * HWl + (C - LO);
                            g_neiList[b*400 + slot] = s | (elem << 2);
                        }
                    }
                }
            }
        }
        __syncthreads();
        if (tid == 0) { g_mainCnt[b] = sCntM; g_neiCnt[b] = sCntN; }
        if (tid < 3)  g_nposPart[b][tid] = sNpos[tid];
        return;
    }

    // Bresenham interleave of dense (4184) and scattered (788) roles across
    // work index r in [0, 4972): keeps both resource classes busy from t=0.
    int r = blockIdx.x - NB;
    long long lo = ((long long)r       * SCT_BLOCKS) / WORKB;
    long long hi = ((long long)(r + 1) * SCT_BLOCKS) / WORKB;
    bool isScat = (hi > lo);

    if (isScat) {
        // --------------------- scattered role: rows [201600, 403200) -------------
        int sidx = (int)lo;                    // 0..787
        int i = sidx * 256 + tid;
        double a0 = 0.0, a1 = 0.0, a2 = 0.0;
        if (i < 201600) {
            int n = 201600 + i;
            const float* out; int loc; int s;
            if (n < 307200)      { out = o0; loc = n;          s = 0; }
            else if (n < 384000) { out = o1; loc = n - 307200; s = 1; }
            else                 { out = o2; loc = n - 384000; s = 2; }
            double v = (double)softplusf(out[(size_t)loc * 85 + 4]);
            if (s == 0) a0 = v; else if (s == 1) a1 = v; else a2 = v;
        }
        a0 = wred64(a0); a1 = wred64(a1); a2 = wred64(a2);
        if ((tid & 63) == 0) { int wv = tid >> 6; sRed[wv][0]=a0; sRed[wv][1]=a1; sRed[wv][2]=a2; }
        __syncthreads();
        if (tid == 0) {
            #pragma unroll
            for (int s = 0; s < 3; ++s)
                g_gpart[sidx][s] = sRed[0][s] + sRed[1][s] + sRed[2][s] + sRed[3][s];
        }
    } else {
        // --------------------- dense role: o0 f4 [0, 4284000) --------------------
        int didx = r - (int)lo;                // 0..4183
        int S0 = didx * 1024;                  // slab start (f4), block-uniform
        float4* ldsv = (float4*)ldsStage;
        const float4* T = (const float4*)o0;
        #pragma unroll
        for (int k = 0; k < 4; ++k) {
            int idx = S0 + k*256 + tid;        // max 4,284,415 < 6,528,000: safe read
            ldsv[k*256 + tid] = T[idx];
        }
        __syncthreads();
        int e0   = 4 * S0;
        int off0 = (4 - (e0 % 85) + 85) % 85;  // first obj offset within slab (SALU)
        int valid = 4 * (min(NF4D, S0 + 1024) - S0);   // extraction bound (no overlap)
        double acc = 0.0;
        int el = off0 + 85 * tid;              // threads 0..~48 in range
        if (el < valid) acc = (double)softplusf(ldsStage[el]);
        acc = wred64(acc);
        if ((tid & 63) == 0) sRed[tid >> 6][0] = acc;
        __syncthreads();
        if (tid == 0) g_dpart[didx] = sRed[0][0] + sRed[1][0] + sRed[2][0] + sRed[3][0];
    }
}

// =============== Kernel B: poswork + neighbor corr + finalize (fences only here) ====
__global__ __launch_bounds__(256) void k_rest(const float* __restrict__ o0,
                                              const float* __restrict__ o1,
                                              const float* __restrict__ o2,
                                              float* __restrict__ d_out) {
    int tid = threadIdx.x;
    if (blockIdx.x < POS_BLOCKS) {
        __shared__ double sPB[4], sPC[4], sPO[4];
        __shared__ int    sPS[4];
        int wv = tid >> 6, lane = tid & 63;
        int w = blockIdx.x * 4 + wv;          // [0, 1600)
        int b = w / NT, slot = w % NT;
        double bsum = 0.0, csum = 0.0, osum = 0.0;
        int sidx = -1;
        if (slot < g_mainCnt[b]) {
            int gidx = b*NT + slot;
            int n = g_recN[gidx];
            int s, bb, cij, HW;
            const float* out;
            if (n < 102400)      { s=0; HW=6400; int l=n;          bb=l/6400; cij=l%6400; out=o0; }
            else if (n < 128000) { s=1; HW=1600; int l=n-102400;   bb=l/1600; cij=l%1600; out=o1; }
            else                 { s=2; HW=400;  int l=n-128000;   bb=l/400;  cij=l%400;  out=o2; }
            sidx = s;
            const float* base = out + ((size_t)(bb * NA * HW) + (size_t)cij) * 85;
            float v0 = base[lane];
            float v1 = (lane < 21) ? base[64 + lane] : 0.0f;

            uint4  mm = g_recM[gidx];
            float4 bt = g_recB[gidx];
            float  sw = g_recW[gidx];

            float cl_ = 0.0f;
            if (lane >= 5) {
                int c = lane - 5;
                unsigned bit = ((c < 32) ? (mm.x >> c) : (mm.y >> (c-32))) & 1u;
                cl_ += softplusf(v0) - (bit ? v0 : 0.0f);
            }
            if (lane < 21) {
                int c = lane + 59;
                unsigned bit = ((c < 64) ? (mm.y >> (c-32)) : (mm.z >> (c-64))) & 1u;
                cl_ += softplusf(v1) - (bit ? v1 : 0.0f);
            }

            float pv = 1.0f / (1.0f + expf(-v0));
            float pb0 = __shfl(pv, 0), pb1 = __shfl(pv, 1);
            float pb2 = __shfl(pv, 2), pb3 = __shfl(pv, 3);
            float x4  = __shfl(v0, 4);   // obj logit, tv = 1.0

            #pragma unroll
            for (int o = 32; o > 0; o >>= 1) cl_ += __shfl_xor(cl_, o);

            if (lane == 0) {
                float btv[4] = {bt.x, bt.y, bt.z, bt.w};
                float pb[4]  = {pb0, pb1, pb2, pb3};
                float l1 = 0.0f;
                #pragma unroll
                for (int k = 0; k < 4; ++k) {
                    float d = pb[k] - btv[k];
                    float ad = fabsf(d);
                    l1 += (ad < 1.0f) ? (0.5f*d*d) : (ad - 0.5f);
                }
                l1 *= 0.25f;
                float ix1 = fmaxf(pb0, bt.x), iy1 = fmaxf(pb1, bt.y);
                float ix2 = fminf(pb2, bt.z), iy2 = fminf(pb3, bt.w);
                float inter = fmaxf(ix2-ix1, 0.f) * fmaxf(iy2-iy1, 0.f);
                float aa1 = fmaxf(pb2-pb0, 0.f) * fmaxf(pb3-pb1, 0.f);
                float aa2 = fmaxf(bt.z-bt.x, 0.f) * fmaxf(bt.w-bt.y, 0.f);
                float iou = inter / (aa1 + aa2 - inter + 1e-6f);
                bsum = (double)((l1 + 1.0f - iou) * sw);
                csum = (double)(cl_ * (1.0f / (float)NCLS) * sw);
                osum = -(double)x4;
            }
        }
        if (lane == 0) { sPB[wv]=bsum; sPC[wv]=csum; sPO[wv]=osum; sPS[wv]=sidx; }
        __syncthreads();
        if (tid == 0) {
            int pb_ = blockIdx.x;
            double B0=0,B1=0,B2=0, C0=0,C1=0,C2=0, O0s=0,O1s=0,O2s=0;
            #pragma unroll
            for (int i = 0; i < 4; ++i) {
                int si = sPS[i];
                if (si == 0)      { B0+=sPB[i]; C0+=sPC[i]; O0s+=sPO[i]; }
                else if (si == 1) { B1+=sPB[i]; C1+=sPC[i]; O1s+=sPO[i]; }
                else if (si == 2) { B2+=sPB[i]; C2+=sPC[i]; O2s+=sPO[i]; }
            }
            g_bpart[pb_][0]=B0; g_bpart[pb_][1]=B1; g_bpart[pb_][2]=B2;
            g_cpart[pb_][0]=C0; g_cpart[pb_][1]=C1; g_cpart[pb_][2]=C2;
            g_opart[pb_][0]=O0s; g_opart[pb_][1]=O1s; g_opart[pb_][2]=O2s;
        }
    } else {
        __shared__ double sN[4][3];
        int nb = blockIdx.x - POS_BLOCKS;     // 0..15
        double c0 = 0.0, c1 = 0.0, c2 = 0.0;
        #pragma unroll
        for (int r = 0; r < 2; ++r) {
            int e = nb*256 + tid + r*4096;    // covers [0, 6400)
            if (e < NB*400) {
                int b = e / 400, slot = e % 400;
                if (slot < g_neiCnt[b]) {
                    int rec = g_neiList[e];
                    int s = rec & 3;
                    int elem = rec >> 2;
                    const float* out = (s==0) ? o0 : ((s==1) ? o1 : o2);
                    double v = 0.5 * (double)out[(size_t)elem * 85 + 4];
                    if (s == 0) c0 -= v; else if (s == 1) c1 -= v; else c2 -= v;
                }
            }
        }
        c0 = wred64(c0); c1 = wred64(c1); c2 = wred64(c2);
        if ((tid & 63) == 0) { int wv = tid>>6; sN[wv][0]=c0; sN[wv][1]=c1; sN[wv][2]=c2; }
        __syncthreads();
        if (tid == 0) {
            #pragma unroll
            for (int s = 0; s < 3; ++s)
                g_ncorrPart[nb][s] = sN[0][s] + sN[1][s] + sN[2][s] + sN[3][s];
        }
    }

    // ---------- done-counter finalize ----------
    __shared__ int sLast;
    if (tid == 0) {
        __threadfence();
        unsigned old = atomicAdd(&g_done, 1u);
        sLast = (old == (unsigned)(REST_TOTAL - 1)) ? 1 : 0;
    }
    __syncthreads();
    if (sLast) {
        __threadfence();
        __shared__ double sF[4][12];
        __shared__ int    sI[4][3];
        double oS0=0,oS1=0,oS2=0, bS0=0,bS1=0,bS2=0, cS0=0,cS1=0,cS2=0, oC0=0,oC1=0,oC2=0;
        int n0=0, n1=0, n2=0;
        for (int r = tid; r < DEN_BLOCKS; r += 256) oS0 += g_dpart[r];
        for (int r = tid; r < SCT_BLOCKS; r += 256) {
            oS0 += g_gpart[r][0]; oS1 += g_gpart[r][1]; oS2 += g_gpart[r][2];
        }
        for (int r = tid; r < POS_BLOCKS; r += 256) {
            bS0 += g_bpart[r][0]; bS1 += g_bpart[r][1]; bS2 += g_bpart[r][2];
            cS0 += g_cpart[r][0]; cS1 += g_cpart[r][1]; cS2 += g_cpart[r][2];
            oC0 += g_opart[r][0]; oC1 += g_opart[r][1]; oC2 += g_opart[r][2];
        }
        if (tid < NEI_BLOCKS) {
            oC0 += g_ncorrPart[tid][0]; oC1 += g_ncorrPart[tid][1]; oC2 += g_ncorrPart[tid][2];
        }
        if (tid < NB) {
            n0 += g_nposPart[tid][0]; n1 += g_nposPart[tid][1]; n2 += g_nposPart[tid][2];
        }
        oS0=wred64(oS0); oS1=wred64(oS1); oS2=wred64(oS2);
        bS0=wred64(bS0); bS1=wred64(bS1); bS2=wred64(bS2);
        cS0=wred64(cS0); cS1=wred64(cS1); cS2=wred64(cS2);
        oC0=wred64(oC0); oC1=wred64(oC1); oC2=wred64(oC2);
        n0=wredi(n0); n1=wredi(n1); n2=wredi(n2);
        if ((tid & 63) == 0) {
            int wv = tid >> 6;
            sF[wv][0]=oS0; sF[wv][1]=oS1; sF[wv][2]=oS2;
            sF[wv][3]=bS0; sF[wv][4]=bS1; sF[wv][5]=bS2;
            sF[wv][6]=cS0; sF[wv][7]=cS1; sF[wv][8]=cS2;
            sF[wv][9]=oC0; sF[wv][10]=oC1; sF[wv][11]=oC2;
            sI[wv][0]=n0; sI[wv][1]=n1; sI[wv][2]=n2;
        }
        __syncthreads();
        if (tid == 0) {
            double f[12];
            #pragma unroll
            for (int j = 0; j < 12; ++j) f[j] = sF[0][j] + sF[1][j] + sF[2][j] + sF[3][j];
            int np[3];
            #pragma unroll
            for (int s = 0; s < 3; ++s) np[s] = sI[0][s] + sI[1][s] + sI[2][s] + sI[3][s];
            const double cells[3] = {307200.0, 76800.0, 19200.0};
            double bl = 0.0, ol = 0.0, cl = 0.0;
            #pragma unroll
            for (int s = 0; s < 3; ++s) {
                ol += (f[s] + f[9+s]) / cells[s];
                if (np[s] > 0) {
                    double denom = (double)np[s];
                    bl += f[3+s] / denom;
                    cl += f[6+s] / denom;
                }
            }
            bl /= 3.0; ol /= 3.0; cl /= 3.0;
            double fin = 5.0*bl + 1.0*ol + 1.0*cl;
            d_out[0] = (float)fin;
            d_out[1] = (float)bl;
            d_out[2] = (float)ol;
            d_out[3] = (float)cl;
        }
    }
}

extern "C" void kernel_launch(void* const* d_in, const int* in_sizes, int n_in,
                              void* d_out, int out_size, void* d_ws, size_t ws_size,
                              hipStream_t stream) {
    const float* o0 = (const float*)d_in[0];
    const float* o1 = (const float*)d_in[1];
    const float* o2 = (const float*)d_in[2];
    const float* tg = (const float*)d_in[3];
    float* outp = (float*)d_out;

    kA    <<<A_TOTAL, 256, 0, stream>>>(o0, o1, o2, tg);
    k_rest<<<REST_TOTAL, 256, 0, stream>>>(o0, o1, o2, outp);
}

// Round 14
// 61.713 us; speedup vs baseline: 1.1361x; 1.1361x over previous
//
#include <hip/hip_runtime.h>
#include <math.h>

#define NCLS 80
#define NB 16
#define NA 3
#define NT 100

static constexpr int GAT_BLOCKS = 1575;         // 403200 / 256, 1 load/thread
static constexpr int POS_BLOCKS = 400;          // 1600 waves
static constexpr int NEI_BLOCKS = 16;
static constexpr int REST_TOTAL = POS_BLOCKS + NEI_BLOCKS;  // 416

static constexpr int OBJ_OFF1 = 307200;         // gather block 1200 boundary
static constexpr int OBJ_OFF2 = 384000;         // gather block 1500 boundary

// local (per-image) cell encoding: s0 [0,6400), s1 [6400,8000), s2 [8000,8400)

__device__ double g_spart[GAT_BLOCKS];     // gather partials (plain stores)
__device__ int    g_mainCnt[NB];
__device__ int    g_neiCnt [NB];
__device__ int    g_recN[NB*NT];           // global cell index of main winner
__device__ float  g_recW[NB*NT];           // weight (winner target)
__device__ float4 g_recB[NB*NT];           // bvec of lastAny target
__device__ uint4  g_recM[NB*NT];           // class mask words
__device__ int    g_neiList[NB*400];       // s | (objElem<<2)
__device__ double g_bpart[POS_BLOCKS][3];
__device__ double g_cpart[POS_BLOCKS][3];
__device__ double g_opart[POS_BLOCKS][3];
__device__ double g_ncorrPart[NEI_BLOCKS][3];
__device__ int    g_nposPart[NB][3];
__device__ unsigned g_done;                // reset by k_winner block 0 each call

__device__ __forceinline__ float softplusf(float x) {
    return fmaxf(x, 0.0f) + log1pf(expf(-fabsf(x)));   // stable logaddexp(0,x)
}
__device__ __forceinline__ double wred64(double v) {
    #pragma unroll
    for (int o = 32; o > 0; o >>= 1) v += __shfl_xor(v, o);
    return v;
}
__device__ __forceinline__ int wredi(int v) {
    #pragma unroll
    for (int o = 32; o > 0; o >>= 1) v += __shfl_xor(v, o);
    return v;
}

// =============== K1: pure strided gather — 1 load/thread, no fences/atomics ========
__global__ __launch_bounds__(256) void k_gather(const float* __restrict__ o0,
                                                const float* __restrict__ o1,
                                                const float* __restrict__ o2) {
    __shared__ double sw4[4];
    int tid = threadIdx.x;
    int n = blockIdx.x * 256 + tid;            // [0, 403200)
    const float* out; int loc;
    if (n < OBJ_OFF1)      { out = o0; loc = n; }
    else if (n < OBJ_OFF2) { out = o1; loc = n - OBJ_OFF1; }
    else                   { out = o2; loc = n - OBJ_OFF2; }
    float x = out[(size_t)loc * 85 + 4];
    double v = wred64((double)softplusf(x));
    if ((tid & 63) == 0) sw4[tid >> 6] = v;
    __syncthreads();
    if (tid == 0) g_spart[blockIdx.x] = sw4[0] + sw4[1] + sw4[2] + sw4[3];
}

// =============== K2: winner resolution — packed, branchless, unrollable ============
// sPK[t] = cell(14b) | valid<<14 | tiny<<15 | cid<<16 (8b) | clsok<<24
__global__ __launch_bounds__(512) void k_winner(const float* __restrict__ tgt) {
    __shared__ int   sPK[NT];
    __shared__ int4  sNC[NT];
    __shared__ float sB4[NT][4];
    __shared__ float sWt[NT];
    __shared__ int   sCntM, sCntN, sNpos[3];
    int b = blockIdx.x, tid = threadIdx.x;
    if (tid == 0) { sCntM = 0; sCntN = 0; if (b == 0) g_done = 0u; }
    if (tid < 3) sNpos[tid] = 0;
    if (tid < NT) {
        const float* p = tgt + (size_t)(b*NT + tid) * 5;
        float x1 = fminf(fmaxf(p[0],0.f),1.f);
        float y1 = fminf(fmaxf(p[1],0.f),1.f);
        float x2 = fminf(fmaxf(p[2],0.f),1.f);
        float y2 = fminf(fmaxf(p[3],0.f),1.f);
        bool valid = (x2 > x1) && (y2 > y1);
        int pk = 0;
        int4 nc = make_int4(-1,-1,-1,-1);
        float area = 0.f;
        if (valid) {
            area = (x2-x1)*(y2-y1);
            int s  = (area <= 0.0025f) ? 0 : ((area <= 0.0225f) ? 1 : 2);
            int Wd = (s==0) ? 80 : ((s==1) ? 40 : 20);
            int LO = (s==0) ? 0  : ((s==1) ? 6400 : 8000);
            int gi = (int)floorf(0.5f*(x1+x2)*(float)Wd); gi = min(max(gi,0), Wd-1);
            int gj = (int)floorf(0.5f*(y1+y2)*(float)Wd); gj = min(max(gj,0), Wd-1);
            int cell = LO + gj*Wd + gi;
            int cid = (int)p[4];
            int clsok = (cid >= 0 && cid < NCLS) ? 1 : 0;
            int cidc = min(max(cid, 0), NCLS-1);
            int tiny = (area <= 0.0025f) ? 1 : 0;
            pk = cell | (1<<14) | (tiny<<15) | (cidc<<16) | (clsok<<24);
            if (tiny) {
                nc.x = (gj-1 >= 0) ? (LO + (gj-1)*Wd + gi) : -1;
                nc.y = (gj+1 < Wd) ? (LO + (gj+1)*Wd + gi) : -1;
                nc.z = (gi-1 >= 0) ? (LO + gj*Wd + gi-1)   : -1;
                nc.w = (gi+1 < Wd) ? (LO + gj*Wd + gi+1)   : -1;
            }
        }
        float smallness = 1.f - fminf(1.f, area / 0.0025f);
        sPK[tid] = pk; sNC[tid] = nc;
        sWt[tid] = 1.f + fmaxf(0.f, smallness);
        sB4[tid][0]=x1; sB4[tid][1]=y1; sB4[tid][2]=x2; sB4[tid][3]=y2;
    }
    __syncthreads();
    if (tid < NT) {
        // -------- main event for target t: winner iff no later valid main on C ------
        int t = tid;
        int me = sPK[t];
        if (me & (1<<14)) {
            int C = me & 0x3FFF;
            bool lose = false; int la = t;
            unsigned m0=0, m1=0, m2=0;
            #pragma unroll 4
            for (int t2 = 0; t2 < NT; ++t2) {
                int  w2 = sPK[t2];
                int4 n2 = sNC[t2];
                int  c2 = w2 & 0x3FFF;
                bool v2 = (w2 & (1<<14)) != 0;
                bool isMain = v2 && (c2 == C);
                bool tch = (n2.x==C) | (n2.y==C) | (n2.z==C) | (n2.w==C);
                bool touch = isMain | tch;
                lose = lose | (isMain && (t2 > t));
                if (touch) {
                    if (t2 > la) la = t2;
                    if (w2 & (1<<24)) {
                        int cd = (w2 >> 16) & 0xFF;
                        if (cd < 32)      m0 |= 1u << cd;
                        else if (cd < 64) m1 |= 1u << (cd-32);
                        else              m2 |= 1u << (cd-64);
                    }
                }
            }
            if (!lose) {
                int slot = atomicAdd(&sCntM, 1);
                int s   = (C < 6400) ? 0 : ((C < 8000) ? 1 : 2);
                int LO  = (s==0) ? 0 : ((s==1) ? 6400 : 8000);
                int HWl = (s==0) ? 6400 : ((s==1) ? 1600 : 400);
                int GO  = (s==0) ? 0 : ((s==1) ? 102400 : 128000);
                int gidx = b*NT + slot;
                g_recN[gidx] = GO + b*HWl + (C - LO);
                g_recW[gidx] = sWt[t];
                g_recB[gidx] = make_float4(sB4[la][0], sB4[la][1], sB4[la][2], sB4[la][3]);
                g_recM[gidx] = make_uint4(m0, m1, m2, 0u);
                atomicAdd(&sNpos[s], 1);
            }
        }
    } else if (tid < 100 + 400) {
        // -------- neighbor event (t, k): winner iff no main ever on C and no later toucher
        int idx = tid - 100, t = idx >> 2, k = idx & 3;
        int me = sPK[t];
        if (me & (1<<15)) {    // tiny (implies valid)
            int4 myn = sNC[t];
            int C = (k==0) ? myn.x : ((k==1) ? myn.y : ((k==2) ? myn.z : myn.w));
            if (C >= 0) {
                bool dead = false;
                #pragma unroll 4
                for (int t2 = 0; t2 < NT; ++t2) {
                    int  w2 = sPK[t2];
                    int4 n2 = sNC[t2];
                    bool v2 = (w2 & (1<<14)) != 0;
                    int  c2 = w2 & 0x3FFF;
                    dead = dead | (v2 && (c2 == C));
                    dead = dead | ((t2 > t) && ((n2.x==C)|(n2.y==C)|(n2.z==C)|(n2.w==C)));
                }
                if (!dead) {
                    int slot = atomicAdd(&sCntN, 1);
                    int s   = (C < 6400) ? 0 : ((C < 8000) ? 1 : 2);
                    int LO  = (s==0) ? 0 : ((s==1) ? 6400 : 8000);
                    int HWl = (s==0) ? 6400 : ((s==1) ? 1600 : 400);
                    int elem = b * NA * HWl + (C - LO);
                    g_neiList[b*400 + slot] = s | (elem << 2);
                }
            }
        }
    }
    __syncthreads();
    if (tid == 0) { g_mainCnt[b] = sCntM; g_neiCnt[b] = sCntN; }
    if (tid < 3)  g_nposPart[b][tid] = sNpos[tid];
}

// =============== K3: poswork + neighbor corr + finalize (fences only here) =========
__global__ __launch_bounds__(256) void k_rest(const float* __restrict__ o0,
                                              const float* __restrict__ o1,
                                              const float* __restrict__ o2,
                                              float* __restrict__ d_out) {
    int tid = threadIdx.x;
    if (blockIdx.x < POS_BLOCKS) {
        __shared__ double sPB[4], sPC[4], sPO[4];
        __shared__ int    sPS[4];
        int wv = tid >> 6, lane = tid & 63;
        int w = blockIdx.x * 4 + wv;          // [0, 1600)
        int b = w / NT, slot = w % NT;
        double bsum = 0.0, csum = 0.0, osum = 0.0;
        int sidx = -1;
        if (slot < g_mainCnt[b]) {
            int gidx = b*NT + slot;
            int n = g_recN[gidx];
            int s, bb, cij, HW;
            const float* out;
            if (n < 102400)      { s=0; HW=6400; int l=n;          bb=l/6400; cij=l%6400; out=o0; }
            else if (n < 128000) { s=1; HW=1600; int l=n-102400;   bb=l/1600; cij=l%1600; out=o1; }
            else                 { s=2; HW=400;  int l=n-128000;   bb=l/400;  cij=l%400;  out=o2; }
            sidx = s;
            const float* base = out + ((size_t)(bb * NA * HW) + (size_t)cij) * 85;
            float v0 = base[lane];
            float v1 = (lane < 21) ? base[64 + lane] : 0.0f;

            uint4  mm = g_recM[gidx];
            float4 bt = g_recB[gidx];
            float  sw = g_recW[gidx];

            float cl_ = 0.0f;
            if (lane >= 5) {
                int c = lane - 5;
                unsigned bit = ((c < 32) ? (mm.x >> c) : (mm.y >> (c-32))) & 1u;
                cl_ += softplusf(v0) - (bit ? v0 : 0.0f);
            }
            if (lane < 21) {
                int c = lane + 59;
                unsigned bit = ((c < 64) ? (mm.y >> (c-32)) : (mm.z >> (c-64))) & 1u;
                cl_ += softplusf(v1) - (bit ? v1 : 0.0f);
            }

            float pv = 1.0f / (1.0f + expf(-v0));
            float pb0 = __shfl(pv, 0), pb1 = __shfl(pv, 1);
            float pb2 = __shfl(pv, 2), pb3 = __shfl(pv, 3);
            float x4  = __shfl(v0, 4);   // obj logit, tv = 1.0

            #pragma unroll
            for (int o = 32; o > 0; o >>= 1) cl_ += __shfl_xor(cl_, o);

            if (lane == 0) {
                float btv[4] = {bt.x, bt.y, bt.z, bt.w};
                float pb[4]  = {pb0, pb1, pb2, pb3};
                float l1 = 0.0f;
                #pragma unroll
                for (int k = 0; k < 4; ++k) {
                    float d = pb[k] - btv[k];
                    float ad = fabsf(d);
                    l1 += (ad < 1.0f) ? (0.5f*d*d) : (ad - 0.5f);
                }
                l1 *= 0.25f;
                float ix1 = fmaxf(pb0, bt.x), iy1 = fmaxf(pb1, bt.y);
                float ix2 = fminf(pb2, bt.z), iy2 = fminf(pb3, bt.w);
                float inter = fmaxf(ix2-ix1, 0.f) * fmaxf(iy2-iy1, 0.f);
                float aa1 = fmaxf(pb2-pb0, 0.f) * fmaxf(pb3-pb1, 0.f);
                float aa2 = fmaxf(bt.z-bt.x, 0.f) * fmaxf(bt.w-bt.y, 0.f);
                float iou = inter / (aa1 + aa2 - inter + 1e-6f);
                bsum = (double)((l1 + 1.0f - iou) * sw);
                csum = (double)(cl_ * (1.0f / (float)NCLS) * sw);
                osum = -(double)x4;
            }
        }
        if (lane == 0) { sPB[wv]=bsum; sPC[wv]=csum; sPO[wv]=osum; sPS[wv]=sidx; }
        __syncthreads();
        if (tid == 0) {
            int pb_ = blockIdx.x;
            double B0=0,B1=0,B2=0, C0=0,C1=0,C2=0, O0s=0,O1s=0,O2s=0;
            #pragma unroll
            for (int i = 0; i < 4; ++i) {
                int si = sPS[i];
                if (si == 0)      { B0+=sPB[i]; C0+=sPC[i]; O0s+=sPO[i]; }
                else if (si == 1) { B1+=sPB[i]; C1+=sPC[i]; O1s+=sPO[i]; }
                else if (si == 2) { B2+=sPB[i]; C2+=sPC[i]; O2s+=sPO[i]; }
            }
            g_bpart[pb_][0]=B0; g_bpart[pb_][1]=B1; g_bpart[pb_][2]=B2;
            g_cpart[pb_][0]=C0; g_cpart[pb_][1]=C1; g_cpart[pb_][2]=C2;
            g_opart[pb_][0]=O0s; g_opart[pb_][1]=O1s; g_opart[pb_][2]=O2s;
        }
    } else {
        __shared__ double sN[4][3];
        int nb = blockIdx.x - POS_BLOCKS;     // 0..15
        double c0 = 0.0, c1 = 0.0, c2 = 0.0;
        #pragma unroll
        for (int r = 0; r < 2; ++r) {
            int e = nb*256 + tid + r*4096;    // covers [0, 6400)
            if (e < NB*400) {
                int b = e / 400, slot = e % 400;
                if (slot < g_neiCnt[b]) {
                    int rec = g_neiList[e];
                    int s = rec & 3;
                    int elem = rec >> 2;
                    const float* out = (s==0) ? o0 : ((s==1) ? o1 : o2);
                    double v = 0.5 * (double)out[(size_t)elem * 85 + 4];
                    if (s == 0) c0 -= v; else if (s == 1) c1 -= v; else c2 -= v;
                }
            }
        }
        c0 = wred64(c0); c1 = wred64(c1); c2 = wred64(c2);
        if ((tid & 63) == 0) { int wv = tid>>6; sN[wv][0]=c0; sN[wv][1]=c1; sN[wv][2]=c2; }
        __syncthreads();
        if (tid == 0) {
            #pragma unroll
            for (int s = 0; s < 3; ++s)
                g_ncorrPart[nb][s] = sN[0][s] + sN[1][s] + sN[2][s] + sN[3][s];
        }
    }

    // ---------- done-counter finalize ----------
    __shared__ int sLast;
    if (tid == 0) {
        __threadfence();
        unsigned old = atomicAdd(&g_done, 1u);
        sLast = (old == (unsigned)(REST_TOTAL - 1)) ? 1 : 0;
    }
    __syncthreads();
    if (sLast) {
        __threadfence();
        __shared__ double sF[4][12];
        __shared__ int    sI[4][3];
        double oS0=0,oS1=0,oS2=0, bS0=0,bS1=0,bS2=0, cS0=0,cS1=0,cS2=0, oC0=0,oC1=0,oC2=0;
        int n0=0, n1=0, n2=0;
        for (int r = tid; r < GAT_BLOCKS; r += 256) {
            double p = g_spart[r];
            if (r < 1200) oS0 += p; else if (r < 1500) oS1 += p; else oS2 += p;
        }
        for (int r = tid; r < POS_BLOCKS; r += 256) {
            bS0 += g_bpart[r][0]; bS1 += g_bpart[r][1]; bS2 += g_bpart[r][2];
            cS0 += g_cpart[r][0]; cS1 += g_cpart[r][1]; cS2 += g_cpart[r][2];
            oC0 += g_opart[r][0]; oC1 += g_opart[r][1]; oC2 += g_opart[r][2];
        }
        if (tid < NEI_BLOCKS) {
            oC0 += g_ncorrPart[tid][0]; oC1 += g_ncorrPart[tid][1]; oC2 += g_ncorrPart[tid][2];
        }
        if (tid < NB) {
            n0 += g_nposPart[tid][0]; n1 += g_nposPart[tid][1]; n2 += g_nposPart[tid][2];
        }
        oS0=wred64(oS0); oS1=wred64(oS1); oS2=wred64(oS2);
        bS0=wred64(bS0); bS1=wred64(bS1); bS2=wred64(bS2);
        cS0=wred64(cS0); cS1=wred64(cS1); cS2=wred64(cS2);
        oC0=wred64(oC0); oC1=wred64(oC1); oC2=wred64(oC2);
        n0=wredi(n0); n1=wredi(n1); n2=wredi(n2);
        if ((tid & 63) == 0) {
            int wv = tid >> 6;
            sF[wv][0]=oS0; sF[wv][1]=oS1; sF[wv][2]=oS2;
            sF[wv][3]=bS0; sF[wv][4]=bS1; sF[wv][5]=bS2;
            sF[wv][6]=cS0; sF[wv][7]=cS1; sF[wv][8]=cS2;
            sF[wv][9]=oC0; sF[wv][10]=oC1; sF[wv][11]=oC2;
            sI[wv][0]=n0; sI[wv][1]=n1; sI[wv][2]=n2;
        }
        __syncthreads();
        if (tid == 0) {
            double f[12];
            #pragma unroll
            for (int j = 0; j < 12; ++j) f[j] = sF[0][j] + sF[1][j] + sF[2][j] + sF[3][j];
            int np[3];
            #pragma unroll
            for (int s = 0; s < 3; ++s) np[s] = sI[0][s] + sI[1][s] + sI[2][s] + sI[3][s];
            const double cells[3] = {307200.0, 76800.0, 19200.0};
            double bl = 0.0, ol = 0.0, cl = 0.0;
            #pragma unroll
            for (int s = 0; s < 3; ++s) {
                ol += (f[s] + f[9+s]) / cells[s];
                if (np[s] > 0) {
                    double denom = (double)np[s];
                    bl += f[3+s] / denom;
                    cl += f[6+s] / denom;
                }
            }
            bl /= 3.0; ol /= 3.0; cl /= 3.0;
            double fin = 5.0*bl + 1.0*ol + 1.0*cl;
            d_out[0] = (float)fin;
            d_out[1] = (float)bl;
            d_out[2] = (float)ol;
            d_out[3] = (float)cl;
        }
    }
}

extern "C" void kernel_launch(void* const* d_in, const int* in_sizes, int n_in,
                              void* d_out, int out_size, void* d_ws, size_t ws_size,
                              hipStream_t stream) {
    const float* o0 = (const float*)d_in[0];
    const float* o1 = (const float*)d_in[1];
    const float* o2 = (const float*)d_in[2];
    const float* tg = (const float*)d_in[3];
    float* outp = (float*)d_out;

    k_gather<<<GAT_BLOCKS, 256, 0, stream>>>(o0, o1, o2);
    k_winner<<<NB, 512, 0, stream>>>(tg);
    k_rest  <<<REST_TOTAL, 256, 0, stream>>>(o0, o1, o2, outp);
}